// Round 1
// baseline (256.031 us; speedup 1.0000x reference)
//
#include <hip/hip_runtime.h>

// ---------------- types / helpers ----------------
typedef __attribute__((ext_vector_type(8))) __bf16 bf16x8;
typedef __attribute__((ext_vector_type(4))) float  f32x4;

#define GPTR(p)   (__attribute__((address_space(1))) void*)(p)
#define LDSPTR(p) (__attribute__((address_space(3))) void*)(p)

__device__ __forceinline__ unsigned short f2bf(float f) {
    union { float f; unsigned u; } v; v.f = f;
    unsigned r = v.u + 0x7FFF + ((v.u >> 16) & 1);   // RNE
    return (unsigned short)(r >> 16);
}

// Problem constants
// B=8 C=512 H=50 W=76 ; padded HP=52 WP=78 ; M=B*H*W=30400 (padded MP=30464)
// K = 9*512 = 4608 ; N = 512
#define MTOT   30400
#define MPAD   30464
#define KTOT   4608

// ---------------- 1) NCHW f32 -> padded NHWC bf16 ----------------
// P[b][yp][xp][c], yp in [0,52), xp in [0,78); borders pre-zeroed by memset.
__global__ __launch_bounds__(256) void pad_transpose(
    const float* __restrict__ in, unsigned short* __restrict__ P)
{
    __shared__ float t[32][33];
    const int tx = threadIdx.x;          // 32
    const int ty = threadIdx.y;          // 8
    const int tix = blockIdx.x % 3;      // x tile
    const int cix = blockIdx.x / 3;      // c tile
    const int y = blockIdx.y;
    const int b = blockIdx.z;
    const int x0 = tix * 32, c0 = cix * 32;

    const int x = x0 + tx;
    if (x < 76) {
#pragma unroll
        for (int i = 0; i < 4; ++i) {
            int c = c0 + ty + i * 8;
            t[ty + i * 8][tx] = in[((b * 512 + c) * 50 + y) * 76 + x];
        }
    }
    __syncthreads();
#pragma unroll
    for (int i = 0; i < 4; ++i) {
        int xr = ty + i * 8;
        int xw = x0 + xr;
        if (xw < 76) {
            P[((b * 52 + y + 1) * 78 + (xw + 1)) * 512 + c0 + tx] = f2bf(t[tx][xr]);
        }
    }
}

// ---------------- 2) conv_w (O,C,3,3) f32 -> Wt[o][kk*512+c] bf16 (B^T layout) ----------------
__global__ __launch_bounds__(256) void wt_transform(
    const float* __restrict__ cw, unsigned short* __restrict__ Wt)
{
    int i = blockIdx.x * 256 + threadIdx.x;       // < 512*4608
    int o = i / KTOT;
    int r = i - o * KTOT;
    int kk = r >> 9;          // 0..8  (ky*3+kx)
    int c  = r & 511;
    Wt[i] = f2bf(cw[(o * 512 + c) * 9 + kk]);
}

// ---------------- 3) head weights -> W2[64][512] bf16 (rows 0..17 cls, 18..53 reg, rest 0) ----------------
__global__ __launch_bounds__(256) void head_wt(
    const float* __restrict__ cls_w, const float* __restrict__ reg_w,
    const float* __restrict__ cls_b, const float* __restrict__ reg_b,
    unsigned short* __restrict__ W2, float* __restrict__ b2)
{
    int i = blockIdx.x * 256 + threadIdx.x;       // < 64*512
    int n = i >> 9, k = i & 511;
    float v = 0.f;
    if (n < 18) v = cls_w[n * 512 + k];
    else if (n < 54) v = reg_w[(n - 18) * 512 + k];
    W2[i] = f2bf(v);
    if (i < 64) {
        float bv = 0.f;
        if (i < 18) bv = cls_b[i];
        else if (i < 54) bv = reg_b[i - 18];
        b2[i] = bv;
    }
}

// ---------------- 4) conv implicit GEMM: F[m][n] = relu(sum_k A[m][k]*Wt[n][k] + bias[n]) ----------------
// 128x128 tile, BK=64, 4 waves (2x2), 16x16x32 bf16 MFMA, global_load_lds width-16 staging.
__global__ __launch_bounds__(256, 2) void conv_gemm(
    const unsigned short* __restrict__ P,    // padded NHWC bf16
    const unsigned short* __restrict__ Wt,   // [512][4608] bf16
    const float* __restrict__ bias,
    unsigned short* __restrict__ F)          // [MPAD][512] bf16
{
    __shared__ __attribute__((aligned(16))) unsigned short As[128 * 64];
    __shared__ __attribute__((aligned(16))) unsigned short Bs[128 * 64];

    const int tid  = threadIdx.x;
    const int lane = tid & 63;
    const int wv   = tid >> 6;            // 0..3
    const int wr   = wv >> 1, wc = wv & 1;
    const int m0   = blockIdx.y * 128;
    const int n0   = blockIdx.x * 128;

    const int lrow  = wv * 8 + (lane >> 3);   // 0..31 (row within a 32-row group)
    const int klane = (lane & 7) * 8;         // element offset within 64-wide K slice

    // Per-thread global base offsets for the 4 A rows and 4 B rows this thread stages.
    int cb[4], nb[4];
#pragma unroll
    for (int j = 0; j < 4; ++j) {
        int m = m0 + lrow + j * 32;
        if (m >= MTOT) m = 0;                 // clamp (stores are guarded)
        int b = m / 3800;
        int r = m - b * 3800;
        int y = r / 76;
        int x = r - y * 76;
        cb[j] = ((b * 52 + y + 1) * 78 + (x + 1)) * 512 + klane;   // center tap
        nb[j] = (n0 + lrow + j * 32) * KTOT + klane;
    }

    f32x4 acc[4][4];
#pragma unroll
    for (int i = 0; i < 4; ++i)
#pragma unroll
        for (int j = 0; j < 4; ++j) acc[i][j] = (f32x4){0.f, 0.f, 0.f, 0.f};

    for (int kb = 0; kb < 72; ++kb) {
        const int kk = kb >> 3;                         // which 3x3 tap
        const int k0 = kb << 6;
        const int dy = kk / 3 - 1, dx = kk % 3 - 1;
        const int offA = (dy * 78 + dx) * 512 + (k0 & 511);

#pragma unroll
        for (int j = 0; j < 4; ++j)
            __builtin_amdgcn_global_load_lds(GPTR(P + cb[j] + offA),
                LDSPTR((char*)As + (wv + j * 4) * 1024), 16, 0, 0);
#pragma unroll
        for (int j = 0; j < 4; ++j)
            __builtin_amdgcn_global_load_lds(GPTR(Wt + nb[j] + k0),
                LDSPTR((char*)Bs + (wv + j * 4) * 1024), 16, 0, 0);

        __syncthreads();

#pragma unroll
        for (int ks = 0; ks < 2; ++ks) {
            const int kloc = ks * 32 + (lane >> 4) * 8;
            bf16x8 av[4], bv[4];
#pragma unroll
            for (int mi = 0; mi < 4; ++mi)
                av[mi] = *(const bf16x8*)(As + (wr * 64 + mi * 16 + (lane & 15)) * 64 + kloc);
#pragma unroll
            for (int ni = 0; ni < 4; ++ni)
                bv[ni] = *(const bf16x8*)(Bs + (wc * 64 + ni * 16 + (lane & 15)) * 64 + kloc);
#pragma unroll
            for (int mi = 0; mi < 4; ++mi)
#pragma unroll
                for (int ni = 0; ni < 4; ++ni)
                    acc[mi][ni] = __builtin_amdgcn_mfma_f32_16x16x32_bf16(
                        av[mi], bv[ni], acc[mi][ni], 0, 0, 0);
        }
        __syncthreads();
    }

    // Epilogue: bias + relu + bf16 store. C layout: col=lane&15, row=(lane>>4)*4+j (m89-verified)
#pragma unroll
    for (int ni = 0; ni < 4; ++ni) {
        const int col = n0 + wc * 64 + ni * 16 + (lane & 15);
        const float bcol = bias[col];
#pragma unroll
        for (int mi = 0; mi < 4; ++mi) {
#pragma unroll
            for (int j = 0; j < 4; ++j) {
                int row = m0 + wr * 64 + mi * 16 + (lane >> 4) * 4 + j;
                if (row < MTOT) {
                    float v = fmaxf(acc[mi][ni][j] + bcol, 0.f);
                    F[row * 512 + col] = f2bf(v);
                }
            }
        }
    }
}

// ---------------- 5) head GEMM (N=54 in 64) + anchor decode ----------------
// Block = 4 waves; wave w computes rows [blk*64 + w*16, +16) x 64 cols.
// A-fragments straight from global (wave covers 16 rows x 64B -> fully-used lines);
// W2 (64KB) is L2-resident and read as B-fragments directly.
__global__ __launch_bounds__(256) void head_decode(
    const unsigned short* __restrict__ F,
    const unsigned short* __restrict__ W2,
    const float* __restrict__ b2,
    const int* __restrict__ img,
    float* __restrict__ out)
{
    __shared__ float S[64][56];
    const int tid  = threadIdx.x;
    const int lane = tid & 63;
    const int wv   = tid >> 6;
    const int mblk = blockIdx.x * 64;
    const int arow = mblk + wv * 16 + (lane & 15);   // <= 30463 < MPAD

    f32x4 acc[4];
#pragma unroll
    for (int ni = 0; ni < 4; ++ni) acc[ni] = (f32x4){0.f, 0.f, 0.f, 0.f};

#pragma unroll 4
    for (int ks = 0; ks < 16; ++ks) {
        const int kloc = ks * 32 + (lane >> 4) * 8;
        bf16x8 a = *(const bf16x8*)(F + arow * 512 + kloc);
#pragma unroll
        for (int ni = 0; ni < 4; ++ni) {
            bf16x8 b = *(const bf16x8*)(W2 + (ni * 16 + (lane & 15)) * 512 + kloc);
            acc[ni] = __builtin_amdgcn_mfma_f32_16x16x32_bf16(a, b, acc[ni], 0, 0, 0);
        }
    }

#pragma unroll
    for (int ni = 0; ni < 4; ++ni) {
        int col = ni * 16 + (lane & 15);
        if (col < 54) {
            float bb = b2[col];
#pragma unroll
            for (int j = 0; j < 4; ++j)
                S[wv * 16 + (lane >> 4) * 4 + j][col] = acc[ni][j] + bb;
        }
    }
    __syncthreads();

    for (int it = tid; it < 576; it += 256) {
        int rowl = it / 9;
        int a    = it - rowl * 9;
        int m = mblk + rowl;
        if (m >= MTOT) continue;
        int b   = m / 3800;
        int rem = m - b * 3800;
        int y = rem / 76;
        int x = rem - y * 76;

        int ri = a / 3, si = a - ri * 3;
        float sqr = (ri == 0) ? 0.70710678118654752f : ((ri == 1) ? 1.f : 1.41421356237309515f);
        float scale = (float)(128 << si);
        float wa = scale / sqr;
        float ha = scale * sqr;
        float ax = (float)x * 16.f + 8.f;
        float ay = (float)y * 16.f + 8.f;

        float r0 = S[rowl][18 + a * 4 + 0];
        float r1 = S[rowl][18 + a * 4 + 1];
        float r2 = S[rowl][18 + a * 4 + 2];
        float r3 = S[rowl][18 + a * 4 + 3];

        float px = ax + r0 * wa;
        float py = ay + r1 * ha;
        float pw = wa * expf(r2);
        float ph = ha * expf(r3);

        float x1 = px - 0.5f * pw, y1 = py - 0.5f * ph;
        float x2 = x1 + pw,        y2 = y1 + ph;
        float imx = (float)img[2 * b], imy = (float)img[2 * b + 1];
        x1 = fminf(fmaxf(x1, 0.f), imx); x2 = fminf(fmaxf(x2, 0.f), imx);
        y1 = fminf(fmaxf(y1, 0.f), imy); y2 = fminf(fmaxf(y2, 0.f), imy);
        float ww = x2 - x1, hh = y2 - y1;
        float cx = x1 + 0.5f * ww, cy = y1 + 0.5f * hh;

        int pidx = b * 34200 + rem * 9 + a;
        ((float4*)out)[pidx] = make_float4(cx, cy, ww, hh);
        float* oc = out + 1094400 + pidx * 2;
        oc[0] = S[rowl][a * 2 + 0];
        oc[1] = S[rowl][a * 2 + 1];
    }
}

// ---------------- launcher ----------------
extern "C" void kernel_launch(void* const* d_in, const int* in_sizes, int n_in,
                              void* d_out, int out_size, void* d_ws, size_t ws_size,
                              hipStream_t stream) {
    const float* fm     = (const float*)d_in[0];
    const float* conv_w = (const float*)d_in[1];
    const float* conv_b = (const float*)d_in[2];
    const float* cls_w  = (const float*)d_in[3];
    const float* cls_b  = (const float*)d_in[4];
    const float* reg_w  = (const float*)d_in[5];
    const float* reg_b  = (const float*)d_in[6];
    const int*   img    = (const int*)d_in[7];
    float* out = (float*)d_out;

    char* ws = (char*)d_ws;
    // layout (bytes):
    // P  : 0          .. 33,226,752   (8*52*78*512 bf16)
    // Wt : 33,226,752 .. 37,945,344   (512*4608 bf16)
    // F  : 37,945,344 .. 69,140,480   (30464*512 bf16)
    // W2 : 69,140,480 .. 69,206,016   (64*512 bf16)
    // b2 : 69,206,016 .. +256
    unsigned short* P  = (unsigned short*)(ws);
    unsigned short* Wt = (unsigned short*)(ws + 33226752);
    unsigned short* F  = (unsigned short*)(ws + 37945344);
    unsigned short* W2 = (unsigned short*)(ws + 69140480);
    float*          b2 = (float*)(ws + 69206016);

    // zero padded borders of P, and the tail rows of F (read by head_decode, never written)
    hipMemsetAsync(P, 0, 33226752, stream);
    hipMemsetAsync((char*)F + (size_t)MTOT * 512 * 2, 0, (size_t)(MPAD - MTOT) * 512 * 2, stream);

    pad_transpose<<<dim3(48, 50, 8), dim3(32, 8, 1), 0, stream>>>(fm, P);
    wt_transform<<<9216, 256, 0, stream>>>(conv_w, Wt);
    head_wt<<<128, 256, 0, stream>>>(cls_w, reg_w, cls_b, reg_b, W2, b2);
    conv_gemm<<<dim3(4, 238, 1), 256, 0, stream>>>(P, Wt, conv_b, F);
    head_decode<<<476, 256, 0, stream>>>(F, W2, b2, img, out);
}

// Round 4
// 201.993 us; speedup vs baseline: 1.2675x; 1.2675x over previous
//
#include <hip/hip_runtime.h>

// ---------------- types / helpers ----------------
typedef __attribute__((ext_vector_type(8))) __bf16 bf16x8;
typedef __attribute__((ext_vector_type(4))) float  f32x4;

#define GPTR(p)   (__attribute__((address_space(1))) void*)(p)
#define LDSPTR(p) (__attribute__((address_space(3))) void*)(p)
#define MFMA16 __builtin_amdgcn_mfma_f32_16x16x32_bf16
// phase boundary: pin schedule, raw barrier (no vmcnt drain), pin again
#define PHB() do { __builtin_amdgcn_sched_barrier(0); __builtin_amdgcn_s_barrier(); __builtin_amdgcn_sched_barrier(0); } while (0)

__device__ __forceinline__ unsigned short f2bf(float f) {
    union { float f; unsigned u; } v; v.f = f;
    unsigned r = v.u + 0x7FFF + ((v.u >> 16) & 1);   // RNE
    return (unsigned short)(r >> 16);
}

// Problem constants
#define MTOT   30400
#define MPAD   30464
#define KTOT   4608
#define NT     72          // K tiles of 64

// ---------------- 1) NCHW f32 -> padded NHWC bf16 ----------------
__global__ __launch_bounds__(256) void pad_transpose(
    const float* __restrict__ in, unsigned short* __restrict__ P)
{
    __shared__ float t[32][33];
    const int tx = threadIdx.x;          // 32
    const int ty = threadIdx.y;          // 8
    const int tix = blockIdx.x % 3;      // x tile
    const int cix = blockIdx.x / 3;      // c tile
    const int y = blockIdx.y;
    const int b = blockIdx.z;
    const int x0 = tix * 32, c0 = cix * 32;

    const int x = x0 + tx;
    if (x < 76) {
#pragma unroll
        for (int i = 0; i < 4; ++i) {
            int c = c0 + ty + i * 8;
            t[ty + i * 8][tx] = in[((b * 512 + c) * 50 + y) * 76 + x];
        }
    }
    __syncthreads();
#pragma unroll
    for (int i = 0; i < 4; ++i) {
        int xr = ty + i * 8;
        int xw = x0 + xr;
        if (xw < 76) {
            P[((b * 52 + y + 1) * 78 + (xw + 1)) * 512 + c0 + tx] = f2bf(t[tx][xr]);
        }
    }
}

// ---------------- 2) conv_w (O,C,3,3) f32 -> Wt[o][kk*512+c] bf16 (B^T layout) ----------------
__global__ __launch_bounds__(256) void wt_transform(
    const float* __restrict__ cw, unsigned short* __restrict__ Wt)
{
    int i = blockIdx.x * 256 + threadIdx.x;       // < 512*4608
    int o = i / KTOT;
    int r = i - o * KTOT;
    int kk = r >> 9;          // 0..8  (ky*3+kx)
    int c  = r & 511;
    Wt[i] = f2bf(cw[(o * 512 + c) * 9 + kk]);
}

// ---------------- 3) head weights -> W2[64][512] bf16 ----------------
__global__ __launch_bounds__(256) void head_wt(
    const float* __restrict__ cls_w, const float* __restrict__ reg_w,
    const float* __restrict__ cls_b, const float* __restrict__ reg_b,
    unsigned short* __restrict__ W2, float* __restrict__ b2)
{
    int i = blockIdx.x * 256 + threadIdx.x;       // < 64*512
    int n = i >> 9, k = i & 511;
    float v = 0.f;
    if (n < 18) v = cls_w[n * 512 + k];
    else if (n < 54) v = reg_w[(n - 18) * 512 + k];
    W2[i] = f2bf(v);
    if (i < 64) {
        float bv = 0.f;
        if (i < 18) bv = cls_b[i];
        else if (i < 54) bv = reg_b[i - 18];
        b2[i] = bv;
    }
}

// ---------------- 4) conv implicit GEMM, 256x256 8-phase template ----------------
// BM=BN=256, BK=64, 8 waves (2M x 4N). LDS 128KB: buf d at d*65536; A at +0 (2
// halves x 16KB), B at +32768. LDS layout: K-major 16x32-elem subtiles (1024B),
// subtile s = R*2+KB (R=row>>4, KB=k>>5), within: row_in*64 + kbyte, XOR'd by 32
// when (row_in & 8)  [st_16x32 swizzle]. global_load_lds dest is LINEAR; the
// swizzle is applied by pre-swizzling the per-lane global SOURCE (rule #21).
__global__ __launch_bounds__(512, 2) void conv_gemm8(
    const unsigned short* __restrict__ P,    // padded NHWC bf16
    const unsigned short* __restrict__ Wt,   // [512][4608] bf16
    const float* __restrict__ bias,
    unsigned short* __restrict__ F)          // [MPAD][512] bf16
{
    __shared__ __attribute__((aligned(1024))) unsigned char lds[131072];

    const int tid = threadIdx.x;
    const int l   = tid & 63;
    const int w   = tid >> 6;          // wave 0..7
    const int wr  = w >> 2;            // M group 0..1 (owns 128 rows = one A half)
    const int nc  = w & 3;             // N group 0..3 (owns 64 cols)
    const int hB  = nc >> 1;           // which B half this wave reads
    const int rB  = (nc & 1) * 4;      // subtile-R base within the B half
    const int m0  = blockIdx.x * 256;
    const int n0  = blockIdx.y * 256;

    // swizzled read lane offset within a 1024B subtile
    const int loff = (l & 15) * 64 + (((l >> 4) * 16) ^ ((l & 8) ? 32 : 0));
    // swizzled stage source k-element offset (inverse of read swizzle)
    const int kelS = ((l & 3) * 8) ^ ((l & 32) ? 16 : 0);

    // Per-thread global base offsets for staging (half h, load j).
    int cbA[2][2], nbB[2][2];
#pragma unroll
    for (int h = 0; h < 2; ++h)
#pragma unroll
        for (int j = 0; j < 2; ++j) {
            const int s    = j * 8 + w;                          // subtile 0..15
            const int rowt = h * 128 + (s >> 1) * 16 + (l >> 2); // row in 256-tile
            int m = m0 + rowt; if (m >= MTOT) m = 0;             // clamp (stores guarded)
            int b = m / 3800; int r = m - b * 3800;
            int y = r / 76;   int x = r - y * 76;
            cbA[h][j] = ((b * 52 + y + 1) * 78 + (x + 1)) * 512 + (s & 1) * 32 + kelS;
            nbB[h][j] = (n0 + rowt) * KTOT + (s & 1) * 32 + kelS;
        }

    auto stA = [&](int t, int h, unsigned char* abase) {
        const int kk  = t >> 3;
        const int tap = ((kk / 3 - 1) * 78 + (kk % 3 - 1)) * 512 + (t & 7) * 64;
#pragma unroll
        for (int j = 0; j < 2; ++j)
            __builtin_amdgcn_global_load_lds(GPTR(P + cbA[h][j] + tap),
                LDSPTR(abase + h * 16384 + j * 8192 + w * 1024), 16, 0, 0);
    };
    auto stB = [&](int t, int h, unsigned char* bbase) {
#pragma unroll
        for (int j = 0; j < 2; ++j)
            __builtin_amdgcn_global_load_lds(GPTR(Wt + nbB[h][j] + t * 64),
                LDSPTR(bbase + h * 16384 + j * 8192 + w * 1024), 16, 0, 0);
    };

    f32x4 acc[8][4];
#pragma unroll
    for (int i = 0; i < 8; ++i)
#pragma unroll
        for (int j = 0; j < 4; ++j) acc[i][j] = (f32x4){0.f, 0.f, 0.f, 0.f};

    // ---- prologue: tile0 (4 half-tiles) + B0(1), A0(1), B1(1); drain to tile0 ----
    {
        unsigned char* A0b = lds;
        unsigned char* B0b = lds + 32768;
        unsigned char* A1b = lds + 65536;
        unsigned char* B1b = lds + 65536 + 32768;
        stA(0, 0, A0b); stA(0, 1, A0b); stB(0, 0, B0b); stB(0, 1, B0b);
        stB(1, 0, B1b); stA(1, 0, A1b); stB(1, 1, B1b);
        __builtin_amdgcn_sched_barrier(0);
        asm volatile("s_waitcnt vmcnt(6)" ::: "memory");   // first 8 loads (= tile 0) landed
        __builtin_amdgcn_s_barrier();
        __builtin_amdgcn_sched_barrier(0);
    }

    // fragment read helper: base points at an A-half or B-half; sub = R*2 region
#define RD(basep, subR, ks) (*(const bf16x8*)((basep) + (((subR) * 2 + (ks)) * 1024) + loff))

    for (int g = 0; g < NT; ++g) {
        unsigned char* Ac = lds + (g & 1) * 65536;
        unsigned char* Bc = Ac + 32768;
        unsigned char* An = lds + (((g & 1) ^ 1)) * 65536;
        unsigned char* Ah = Ac + wr * 16384;   // this wave's A half
        unsigned char* Bh = Bc + hB * 16384;   // this wave's B half

        bf16x8 a[4][2], bb0[2][2], bb1[2][2];

        // ---- P1: read A0 (8) + B0 (4); stage A1(g+1) -> next buf; MFMA A0xB0
#pragma unroll
        for (int f = 0; f < 4; ++f)
#pragma unroll
            for (int ks = 0; ks < 2; ++ks) a[f][ks] = RD(Ah, f, ks);
#pragma unroll
        for (int ni = 0; ni < 2; ++ni)
#pragma unroll
            for (int ks = 0; ks < 2; ++ks) bb0[ni][ks] = RD(Bh, rB + ni, ks);
        if (g < NT - 1) stA(g + 1, 1, An);
        PHB();
        __builtin_amdgcn_s_setprio(1);
#pragma unroll
        for (int f = 0; f < 4; ++f)
#pragma unroll
            for (int ni = 0; ni < 2; ++ni)
#pragma unroll
                for (int ks = 0; ks < 2; ++ks)
                    acc[f][ni] = MFMA16(a[f][ks], bb0[ni][ks], acc[f][ni], 0, 0, 0);
        __builtin_amdgcn_s_setprio(0);
        PHB();

        // ---- P2: read B1 (4); MFMA A0xB1
#pragma unroll
        for (int ni = 0; ni < 2; ++ni)
#pragma unroll
            for (int ks = 0; ks < 2; ++ks) bb1[ni][ks] = RD(Bh, rB + 2 + ni, ks);
        PHB();
        __builtin_amdgcn_s_setprio(1);
#pragma unroll
        for (int f = 0; f < 4; ++f)
#pragma unroll
            for (int ni = 0; ni < 2; ++ni)
#pragma unroll
                for (int ks = 0; ks < 2; ++ks)
                    acc[f][2 + ni] = MFMA16(a[f][ks], bb1[ni][ks], acc[f][2 + ni], 0, 0, 0);
        __builtin_amdgcn_s_setprio(0);
        PHB();

        // ---- P3: read A1 (8, overwrites a[]); stage B0(g+2) -> cur buf (B half0
        //      fully read at end of P2 by all waves); MFMA A1xB1
#pragma unroll
        for (int f = 0; f < 4; ++f)
#pragma unroll
            for (int ks = 0; ks < 2; ++ks) a[f][ks] = RD(Ah, 4 + f, ks);
        if (g < NT - 2) stB(g + 2, 0, Bc);
        PHB();
        __builtin_amdgcn_s_setprio(1);
#pragma unroll
        for (int f = 0; f < 4; ++f)
#pragma unroll
            for (int ni = 0; ni < 2; ++ni)
#pragma unroll
                for (int ks = 0; ks < 2; ++ks)
                    acc[4 + f][2 + ni] = MFMA16(a[f][ks], bb1[ni][ks], acc[4 + f][2 + ni], 0, 0, 0);
        __builtin_amdgcn_s_setprio(0);
        PHB();

        // ---- P4: stage A0(g+2), B1(g+2) -> cur buf (A half0 free after P3,
        //      B half1 free after P2); MFMA A1xB0; counted vmcnt (never 0 mid-loop)
        if (g < NT - 2) { stA(g + 2, 0, Ac); stB(g + 2, 1, Bc); }
        __builtin_amdgcn_s_setprio(1);
#pragma unroll
        for (int f = 0; f < 4; ++f)
#pragma unroll
            for (int ni = 0; ni < 2; ++ni)
#pragma unroll
                for (int ks = 0; ks < 2; ++ks)
                    acc[4 + f][ni] = MFMA16(a[f][ks], bb0[ni][ks], acc[4 + f][ni], 0, 0, 0);
        __builtin_amdgcn_s_setprio(0);
        __builtin_amdgcn_sched_barrier(0);
        if (g < NT - 2)       asm volatile("s_waitcnt vmcnt(6)" ::: "memory");
        else if (g == NT - 2) asm volatile("s_waitcnt vmcnt(0)" ::: "memory");
        __builtin_amdgcn_s_barrier();
        __builtin_amdgcn_sched_barrier(0);
    }
#undef RD

    // ---- epilogue: bias + relu + bf16 store ----
#pragma unroll
    for (int ni = 0; ni < 4; ++ni) {
        const int col = n0 + nc * 64 + ni * 16 + (l & 15);
        const float bcol = bias[col];
#pragma unroll
        for (int mi = 0; mi < 8; ++mi) {
#pragma unroll
            for (int jj = 0; jj < 4; ++jj) {
                const int row = m0 + wr * 128 + mi * 16 + (l >> 4) * 4 + jj;
                if (row < MTOT)
                    F[row * 512 + col] = f2bf(fmaxf(acc[mi][ni][jj] + bcol, 0.f));
            }
        }
    }
}

// ---------------- 5) head GEMM (N=54 in 64) + anchor decode ----------------
__global__ __launch_bounds__(256) void head_decode(
    const unsigned short* __restrict__ F,
    const unsigned short* __restrict__ W2,
    const float* __restrict__ b2,
    const int* __restrict__ img,
    float* __restrict__ out)
{
    __shared__ float S[64][56];
    const int tid  = threadIdx.x;
    const int lane = tid & 63;
    const int wv   = tid >> 6;
    const int mblk = blockIdx.x * 64;
    const int arow = mblk + wv * 16 + (lane & 15);   // < MPAD

    f32x4 acc[4];
#pragma unroll
    for (int ni = 0; ni < 4; ++ni) acc[ni] = (f32x4){0.f, 0.f, 0.f, 0.f};

#pragma unroll 4
    for (int ks = 0; ks < 16; ++ks) {
        const int kloc = ks * 32 + (lane >> 4) * 8;
        bf16x8 a = *(const bf16x8*)(F + arow * 512 + kloc);
#pragma unroll
        for (int ni = 0; ni < 4; ++ni) {
            bf16x8 b = *(const bf16x8*)(W2 + (ni * 16 + (lane & 15)) * 512 + kloc);
            acc[ni] = MFMA16(a, b, acc[ni], 0, 0, 0);
        }
    }

#pragma unroll
    for (int ni = 0; ni < 4; ++ni) {
        int col = ni * 16 + (lane & 15);
        if (col < 54) {
            float bb = b2[col];
#pragma unroll
            for (int j = 0; j < 4; ++j)
                S[wv * 16 + (lane >> 4) * 4 + j][col] = acc[ni][j] + bb;
        }
    }
    __syncthreads();

    for (int it = tid; it < 576; it += 256) {
        int rowl = it / 9;
        int a    = it - rowl * 9;
        int m = mblk + rowl;
        if (m >= MTOT) continue;
        int b   = m / 3800;
        int rem = m - b * 3800;
        int y = rem / 76;
        int x = rem - y * 76;

        int ri = a / 3, si = a - ri * 3;
        float sqr = (ri == 0) ? 0.70710678118654752f : ((ri == 1) ? 1.f : 1.41421356237309515f);
        float scale = (float)(128 << si);
        float wa = scale / sqr;
        float ha = scale * sqr;
        float ax = (float)x * 16.f + 8.f;
        float ay = (float)y * 16.f + 8.f;

        float r0 = S[rowl][18 + a * 4 + 0];
        float r1 = S[rowl][18 + a * 4 + 1];
        float r2 = S[rowl][18 + a * 4 + 2];
        float r3 = S[rowl][18 + a * 4 + 3];

        float px = ax + r0 * wa;
        float py = ay + r1 * ha;
        float pw = wa * expf(r2);
        float ph = ha * expf(r3);

        float x1 = px - 0.5f * pw, y1 = py - 0.5f * ph;
        float x2 = x1 + pw,        y2 = y1 + ph;
        float imx = (float)img[2 * b], imy = (float)img[2 * b + 1];
        x1 = fminf(fmaxf(x1, 0.f), imx); x2 = fminf(fmaxf(x2, 0.f), imx);
        y1 = fminf(fmaxf(y1, 0.f), imy); y2 = fminf(fmaxf(y2, 0.f), imy);
        float ww = x2 - x1, hh = y2 - y1;
        float cx = x1 + 0.5f * ww, cy = y1 + 0.5f * hh;

        int pidx = b * 34200 + rem * 9 + a;
        ((float4*)out)[pidx] = make_float4(cx, cy, ww, hh);
        float* oc = out + 1094400 + pidx * 2;
        oc[0] = S[rowl][a * 2 + 0];
        oc[1] = S[rowl][a * 2 + 1];
    }
}

// ---------------- launcher ----------------
extern "C" void kernel_launch(void* const* d_in, const int* in_sizes, int n_in,
                              void* d_out, int out_size, void* d_ws, size_t ws_size,
                              hipStream_t stream) {
    const float* fm     = (const float*)d_in[0];
    const float* conv_w = (const float*)d_in[1];
    const float* conv_b = (const float*)d_in[2];
    const float* cls_w  = (const float*)d_in[3];
    const float* cls_b  = (const float*)d_in[4];
    const float* reg_w  = (const float*)d_in[5];
    const float* reg_b  = (const float*)d_in[6];
    const int*   img    = (const int*)d_in[7];
    float* out = (float*)d_out;

    char* ws = (char*)d_ws;
    unsigned short* P  = (unsigned short*)(ws);
    unsigned short* Wt = (unsigned short*)(ws + 33226752);
    unsigned short* F  = (unsigned short*)(ws + 37945344);
    unsigned short* W2 = (unsigned short*)(ws + 69140480);
    float*          b2 = (float*)(ws + 69206016);

    hipMemsetAsync(P, 0, 33226752, stream);
    hipMemsetAsync((char*)F + (size_t)MTOT * 512 * 2, 0, (size_t)(MPAD - MTOT) * 512 * 2, stream);

    pad_transpose<<<dim3(48, 50, 8), dim3(32, 8, 1), 0, stream>>>(fm, P);
    wt_transform<<<9216, 256, 0, stream>>>(conv_w, Wt);
    head_wt<<<128, 256, 0, stream>>>(cls_w, reg_w, cls_b, reg_b, W2, b2);
    conv_gemm8<<<dim3(119, 2), 512, 0, stream>>>(P, Wt, conv_b, F);
    head_decode<<<476, 256, 0, stream>>>(F, W2, b2, img, out);
}

// Round 7
// 201.266 us; speedup vs baseline: 1.2721x; 1.0036x over previous
//
#include <hip/hip_runtime.h>

// ---------------- types / helpers ----------------
typedef __attribute__((ext_vector_type(8))) __bf16 bf16x8;
typedef __attribute__((ext_vector_type(4))) float  f32x4;

#define GPTR(p)   (__attribute__((address_space(1))) void*)(p)
#define LDSPTR(p) (__attribute__((address_space(3))) void*)(p)
#define MFMA16 __builtin_amdgcn_mfma_f32_16x16x32_bf16
// phase boundary: pin schedule, raw barrier (no vmcnt drain), pin again
#define PHB() do { __builtin_amdgcn_sched_barrier(0); __builtin_amdgcn_s_barrier(); __builtin_amdgcn_sched_barrier(0); } while (0)

__device__ __forceinline__ unsigned short f2bf(float f) {
    union { float f; unsigned u; } v; v.f = f;
    unsigned r = v.u + 0x7FFF + ((v.u >> 16) & 1);   // RNE
    return (unsigned short)(r >> 16);
}

// Problem constants
#define MTOT   30400
#define MPAD   30464
#define KTOT   4608
#define NT     72          // K tiles of 64

// ---------------- 1) NCHW f32 -> padded NHWC bf16 ----------------
__global__ __launch_bounds__(256) void pad_transpose(
    const float* __restrict__ in, unsigned short* __restrict__ P)
{
    __shared__ float t[32][33];
    const int tx = threadIdx.x;          // 32
    const int ty = threadIdx.y;          // 8
    const int tix = blockIdx.x % 3;      // x tile
    const int cix = blockIdx.x / 3;      // c tile
    const int y = blockIdx.y;
    const int b = blockIdx.z;
    const int x0 = tix * 32, c0 = cix * 32;

    const int x = x0 + tx;
    if (x < 76) {
#pragma unroll
        for (int i = 0; i < 4; ++i) {
            int c = c0 + ty + i * 8;
            t[ty + i * 8][tx] = in[((b * 512 + c) * 50 + y) * 76 + x];
        }
    }
    __syncthreads();
#pragma unroll
    for (int i = 0; i < 4; ++i) {
        int xr = ty + i * 8;
        int xw = x0 + xr;
        if (xw < 76) {
            P[((b * 52 + y + 1) * 78 + (xw + 1)) * 512 + c0 + tx] = f2bf(t[tx][xr]);
        }
    }
}

// ---------------- 1b) zero only the pad borders of P ----------------
// borders: y in {0,51} all x (78+78 segs); x in {0,77}, y=1..50 (50+50 segs).
// 256 segs per batch * 8 batches * 64 float4-chunks of 512 channels.
__global__ __launch_bounds__(256) void border_zero(unsigned short* __restrict__ P)
{
    int i = blockIdx.x * 256 + threadIdx.x;      // < 8*256*64 = 131072
    int b   = i >> 14;
    int rem = i & 16383;
    int seg = rem >> 6;                          // 0..255
    int c8  = (rem & 63) << 3;                   // channel base (8 bf16 per float4)
    int y, x;
    if (seg < 78)       { y = 0;  x = seg; }
    else if (seg < 156) { y = 51; x = seg - 78; }
    else if (seg < 206) { y = seg - 155; x = 0; }    // y=1..50
    else                { y = seg - 205; x = 77; }   // y=1..50
    *(float4*)(P + ((b * 52 + y) * 78 + x) * 512 + c8) = make_float4(0.f, 0.f, 0.f, 0.f);
}

// ---------------- 2) conv_w (O,C,3,3) f32 -> Wt[o][kk*512+c] bf16 (B^T layout) ----------------
__global__ __launch_bounds__(256) void wt_transform(
    const float* __restrict__ cw, unsigned short* __restrict__ Wt)
{
    int i = blockIdx.x * 256 + threadIdx.x;       // < 512*4608
    int o = i / KTOT;
    int r = i - o * KTOT;
    int kk = r >> 9;          // 0..8  (ky*3+kx)
    int c  = r & 511;
    Wt[i] = f2bf(cw[(o * 512 + c) * 9 + kk]);
}

// ---------------- 3) head weights -> W2[64][512] bf16 ----------------
__global__ __launch_bounds__(256) void head_wt(
    const float* __restrict__ cls_w, const float* __restrict__ reg_w,
    const float* __restrict__ cls_b, const float* __restrict__ reg_b,
    unsigned short* __restrict__ W2, float* __restrict__ b2)
{
    int i = blockIdx.x * 256 + threadIdx.x;       // < 64*512
    int n = i >> 9, k = i & 511;
    float v = 0.f;
    if (n < 18) v = cls_w[n * 512 + k];
    else if (n < 54) v = reg_w[(n - 18) * 512 + k];
    W2[i] = f2bf(v);
    if (i < 64) {
        float bv = 0.f;
        if (i < 18) bv = cls_b[i];
        else if (i < 54) bv = reg_b[i - 18];
        b2[i] = bv;
    }
}

// ---------------- 4) conv implicit GEMM, 256x256 8-phase (round-4 schedule) ----------------
// EXACT round-4 (hardware-verified) phase/stage/wait structure. Only deltas vs
// round 4: bijective XCD-chunked block swizzle for m0/n0, and border_zero init.
// BM=BN=256, BK=64, 8 waves (2M x 4N). LDS 128KB: buf d at d*65536; A at +0,
// B at +32768 (2 halves x 16KB). st_16x32 XOR swizzle via pre-swizzled global
// source (rule #21): linear gload_lds dest + inverse-swz source + swz on read.
__global__ __launch_bounds__(512, 2) void conv_gemm8(
    const unsigned short* __restrict__ P,    // padded NHWC bf16
    const unsigned short* __restrict__ Wt,   // [512][4608] bf16
    const float* __restrict__ bias,
    unsigned short* __restrict__ F)          // [MPAD][512] bf16
{
    __shared__ __attribute__((aligned(1024))) unsigned char lds[131072];

    const int tid = threadIdx.x;
    const int l   = tid & 63;
    const int w   = tid >> 6;          // wave 0..7
    const int wr  = w >> 2;            // M group 0..1 (owns 128 rows = one A half)
    const int nc  = w & 3;             // N group 0..3 (owns 64 cols)
    const int hB  = nc >> 1;           // which B half this wave reads
    const int rB  = (nc & 1) * 4;      // subtile-R base within the B half

    // bijective XCD-chunked block swizzle (nwg=238=8*29+6, m204 formula)
    const int orig = blockIdx.y * 119 + blockIdx.x;
    const int xcd = orig & 7, seq = orig >> 3;
    const int wg  = (xcd < 6 ? xcd * 30 : 180 + (xcd - 6) * 29) + seq;
    const int m0  = (wg % 119) * 256;
    const int n0  = (wg / 119) * 256;

    // swizzled read lane offset within a 1024B subtile
    const int loff = (l & 15) * 64 + (((l >> 4) * 16) ^ ((l & 8) ? 32 : 0));
    // swizzled stage source k-element offset (inverse of read swizzle)
    const int kelS = ((l & 3) * 8) ^ ((l & 32) ? 16 : 0);

    // Per-thread global base offsets for staging (half h, load j).
    int cbA[2][2], nbB[2][2];
#pragma unroll
    for (int h = 0; h < 2; ++h)
#pragma unroll
        for (int j = 0; j < 2; ++j) {
            const int s    = j * 8 + w;                          // subtile 0..15
            const int rowt = h * 128 + (s >> 1) * 16 + (l >> 2); // row in 256-tile
            int m = m0 + rowt; if (m >= MTOT) m = 0;             // clamp (stores guarded)
            int b = m / 3800; int r = m - b * 3800;
            int y = r / 76;   int x = r - y * 76;
            cbA[h][j] = ((b * 52 + y + 1) * 78 + (x + 1)) * 512 + (s & 1) * 32 + kelS;
            nbB[h][j] = (n0 + rowt) * KTOT + (s & 1) * 32 + kelS;
        }

    auto stA = [&](int t, int h, unsigned char* abase) {
        const int kk  = t >> 3;
        const int tap = ((kk / 3 - 1) * 78 + (kk % 3 - 1)) * 512 + (t & 7) * 64;
#pragma unroll
        for (int j = 0; j < 2; ++j)
            __builtin_amdgcn_global_load_lds(GPTR(P + cbA[h][j] + tap),
                LDSPTR(abase + h * 16384 + j * 8192 + w * 1024), 16, 0, 0);
    };
    auto stB = [&](int t, int h, unsigned char* bbase) {
#pragma unroll
        for (int j = 0; j < 2; ++j)
            __builtin_amdgcn_global_load_lds(GPTR(Wt + nbB[h][j] + t * 64),
                LDSPTR(bbase + h * 16384 + j * 8192 + w * 1024), 16, 0, 0);
    };

    f32x4 acc[8][4];
#pragma unroll
    for (int i = 0; i < 8; ++i)
#pragma unroll
        for (int j = 0; j < 4; ++j) acc[i][j] = (f32x4){0.f, 0.f, 0.f, 0.f};

    // ---- prologue: tile0 (4 half-tiles) + B0(1), A0(1), B1(1); retire tile0 ----
    {
        unsigned char* A0b = lds;
        unsigned char* B0b = lds + 32768;
        unsigned char* A1b = lds + 65536;
        unsigned char* B1b = lds + 65536 + 32768;
        stA(0, 0, A0b); stA(0, 1, A0b); stB(0, 0, B0b); stB(0, 1, B0b);
        stB(1, 0, B1b); stA(1, 0, A1b); stB(1, 1, B1b);
        __builtin_amdgcn_sched_barrier(0);
        asm volatile("s_waitcnt vmcnt(6)" ::: "memory");   // first 8 loads (= tile 0) landed
        __builtin_amdgcn_s_barrier();
        __builtin_amdgcn_sched_barrier(0);
    }

    // fragment read helper: base points at an A-half or B-half
#define RD(basep, subR, ks) (*(const bf16x8*)((basep) + (((subR) * 2 + (ks)) * 1024) + loff))

    for (int g = 0; g < NT; ++g) {
        unsigned char* Ac = lds + (g & 1) * 65536;
        unsigned char* Bc = Ac + 32768;
        unsigned char* An = lds + (((g & 1) ^ 1)) * 65536;
        unsigned char* Ah = Ac + wr * 16384;   // this wave's A half
        unsigned char* Bh = Bc + hB * 16384;   // this wave's B half

        bf16x8 a[4][2], bb0[2][2], bb1[2][2];

        // ---- P1: read A0 (8) + B0 (4); stage A1(g+1) -> next buf; MFMA A0xB0
#pragma unroll
        for (int f = 0; f < 4; ++f)
#pragma unroll
            for (int ks = 0; ks < 2; ++ks) a[f][ks] = RD(Ah, f, ks);
#pragma unroll
        for (int ni = 0; ni < 2; ++ni)
#pragma unroll
            for (int ks = 0; ks < 2; ++ks) bb0[ni][ks] = RD(Bh, rB + ni, ks);
        if (g < NT - 1) stA(g + 1, 1, An);
        PHB();
        __builtin_amdgcn_s_setprio(1);
#pragma unroll
        for (int f = 0; f < 4; ++f)
#pragma unroll
            for (int ni = 0; ni < 2; ++ni)
#pragma unroll
                for (int ks = 0; ks < 2; ++ks)
                    acc[f][ni] = MFMA16(a[f][ks], bb0[ni][ks], acc[f][ni], 0, 0, 0);
        __builtin_amdgcn_s_setprio(0);
        PHB();

        // ---- P2: read B1 (4); MFMA A0xB1
#pragma unroll
        for (int ni = 0; ni < 2; ++ni)
#pragma unroll
            for (int ks = 0; ks < 2; ++ks) bb1[ni][ks] = RD(Bh, rB + 2 + ni, ks);
        PHB();
        __builtin_amdgcn_s_setprio(1);
#pragma unroll
        for (int f = 0; f < 4; ++f)
#pragma unroll
            for (int ni = 0; ni < 2; ++ni)
#pragma unroll
                for (int ks = 0; ks < 2; ++ks)
                    acc[f][2 + ni] = MFMA16(a[f][ks], bb1[ni][ks], acc[f][2 + ni], 0, 0, 0);
        __builtin_amdgcn_s_setprio(0);
        PHB();

        // ---- P3: read A1 (8, overwrites a[]); stage B0(g+2) -> cur buf (B half0
        //      fully read at end of P2 by all waves, barrier since); MFMA A1xB1
#pragma unroll
        for (int f = 0; f < 4; ++f)
#pragma unroll
            for (int ks = 0; ks < 2; ++ks) a[f][ks] = RD(Ah, 4 + f, ks);
        if (g < NT - 2) stB(g + 2, 0, Bc);
        PHB();
        __builtin_amdgcn_s_setprio(1);
#pragma unroll
        for (int f = 0; f < 4; ++f)
#pragma unroll
            for (int ni = 0; ni < 2; ++ni)
#pragma unroll
                for (int ks = 0; ks < 2; ++ks)
                    acc[4 + f][2 + ni] = MFMA16(a[f][ks], bb1[ni][ks], acc[4 + f][2 + ni], 0, 0, 0);
        __builtin_amdgcn_s_setprio(0);
        PHB();

        // ---- P4: stage A0(g+2), B1(g+2) -> cur buf (A half0 free after P3,
        //      B half1 free after P2, barriers since); MFMA A1xB0; counted vmcnt
        if (g < NT - 2) { stA(g + 2, 0, Ac); stB(g + 2, 1, Bc); }
        __builtin_amdgcn_s_setprio(1);
#pragma unroll
        for (int f = 0; f < 4; ++f)
#pragma unroll
            for (int ni = 0; ni < 2; ++ni)
#pragma unroll
                for (int ks = 0; ks < 2; ++ks)
                    acc[4 + f][ni] = MFMA16(a[f][ks], bb0[ni][ks], acc[4 + f][ni], 0, 0, 0);
        __builtin_amdgcn_s_setprio(0);
        __builtin_amdgcn_sched_barrier(0);
        if (g < NT - 2)       asm volatile("s_waitcnt vmcnt(6)" ::: "memory");
        else if (g == NT - 2) asm volatile("s_waitcnt vmcnt(0)" ::: "memory");
        __builtin_amdgcn_s_barrier();
        __builtin_amdgcn_sched_barrier(0);
    }
#undef RD

    // ---- epilogue: bias + relu + bf16 store ----
#pragma unroll
    for (int ni = 0; ni < 4; ++ni) {
        const int col = n0 + nc * 64 + ni * 16 + (l & 15);
        const float bcol = bias[col];
#pragma unroll
        for (int mi = 0; mi < 8; ++mi) {
#pragma unroll
            for (int jj = 0; jj < 4; ++jj) {
                const int row = m0 + wr * 128 + mi * 16 + (l >> 4) * 4 + jj;
                if (row < MTOT)
                    F[row * 512 + col] = f2bf(fmaxf(acc[mi][ni][jj] + bcol, 0.f));
            }
        }
    }
}

// ---------------- 5) head GEMM (N=54 in 64) + anchor decode ----------------
__global__ __launch_bounds__(256) void head_decode(
    const unsigned short* __restrict__ F,
    const unsigned short* __restrict__ W2,
    const float* __restrict__ b2,
    const int* __restrict__ img,
    float* __restrict__ out)
{
    __shared__ float S[64][56];
    const int tid  = threadIdx.x;
    const int lane = tid & 63;
    const int wv   = tid >> 6;
    const int mblk = blockIdx.x * 64;
    const int arow = mblk + wv * 16 + (lane & 15);   // < MPAD

    f32x4 acc[4];
#pragma unroll
    for (int ni = 0; ni < 4; ++ni) acc[ni] = (f32x4){0.f, 0.f, 0.f, 0.f};

#pragma unroll 4
    for (int ks = 0; ks < 16; ++ks) {
        const int kloc = ks * 32 + (lane >> 4) * 8;
        bf16x8 a = *(const bf16x8*)(F + arow * 512 + kloc);
#pragma unroll
        for (int ni = 0; ni < 4; ++ni) {
            bf16x8 b = *(const bf16x8*)(W2 + (ni * 16 + (lane & 15)) * 512 + kloc);
            acc[ni] = MFMA16(a, b, acc[ni], 0, 0, 0);
        }
    }

#pragma unroll
    for (int ni = 0; ni < 4; ++ni) {
        int col = ni * 16 + (lane & 15);
        if (col < 54) {
            float bb = b2[col];
#pragma unroll
            for (int j = 0; j < 4; ++j)
                S[wv * 16 + (lane >> 4) * 4 + j][col] = acc[ni][j] + bb;
        }
    }
    __syncthreads();

    for (int it = tid; it < 576; it += 256) {
        int rowl = it / 9;
        int a    = it - rowl * 9;
        int m = mblk + rowl;
        if (m >= MTOT) continue;
        int b   = m / 3800;
        int rem = m - b * 3800;
        int y = rem / 76;
        int x = rem - y * 76;

        int ri = a / 3, si = a - ri * 3;
        float sqr = (ri == 0) ? 0.70710678118654752f : ((ri == 1) ? 1.f : 1.41421356237309515f);
        float scale = (float)(128 << si);
        float wa = scale / sqr;
        float ha = scale * sqr;
        float ax = (float)x * 16.f + 8.f;
        float ay = (float)y * 16.f + 8.f;

        float r0 = S[rowl][18 + a * 4 + 0];
        float r1 = S[rowl][18 + a * 4 + 1];
        float r2 = S[rowl][18 + a * 4 + 2];
        float r3 = S[rowl][18 + a * 4 + 3];

        float px = ax + r0 * wa;
        float py = ay + r1 * ha;
        float pw = wa * expf(r2);
        float ph = ha * expf(r3);

        float x1 = px - 0.5f * pw, y1 = py - 0.5f * ph;
        float x2 = x1 + pw,        y2 = y1 + ph;
        float imx = (float)img[2 * b], imy = (float)img[2 * b + 1];
        x1 = fminf(fmaxf(x1, 0.f), imx); x2 = fminf(fmaxf(x2, 0.f), imx);
        y1 = fminf(fmaxf(y1, 0.f), imy); y2 = fminf(fmaxf(y2, 0.f), imy);
        float ww = x2 - x1, hh = y2 - y1;
        float cx = x1 + 0.5f * ww, cy = y1 + 0.5f * hh;

        int pidx = b * 34200 + rem * 9 + a;
        ((float4*)out)[pidx] = make_float4(cx, cy, ww, hh);
        float* oc = out + 1094400 + pidx * 2;
        oc[0] = S[rowl][a * 2 + 0];
        oc[1] = S[rowl][a * 2 + 1];
    }
}

// ---------------- launcher ----------------
extern "C" void kernel_launch(void* const* d_in, const int* in_sizes, int n_in,
                              void* d_out, int out_size, void* d_ws, size_t ws_size,
                              hipStream_t stream) {
    const float* fm     = (const float*)d_in[0];
    const float* conv_w = (const float*)d_in[1];
    const float* conv_b = (const float*)d_in[2];
    const float* cls_w  = (const float*)d_in[3];
    const float* cls_b  = (const float*)d_in[4];
    const float* reg_w  = (const float*)d_in[5];
    const float* reg_b  = (const float*)d_in[6];
    const int*   img    = (const int*)d_in[7];
    float* out = (float*)d_out;

    char* ws = (char*)d_ws;
    unsigned short* P  = (unsigned short*)(ws);
    unsigned short* Wt = (unsigned short*)(ws + 33226752);
    unsigned short* F  = (unsigned short*)(ws + 37945344);
    unsigned short* W2 = (unsigned short*)(ws + 69140480);
    float*          b2 = (float*)(ws + 69206016);

    // zero F tail rows (read by head_decode, never written)
    hipMemsetAsync((char*)F + (size_t)MTOT * 512 * 2, 0, (size_t)(MPAD - MTOT) * 512 * 2, stream);

    border_zero<<<512, 256, 0, stream>>>(P);
    pad_transpose<<<dim3(48, 50, 8), dim3(32, 8, 1), 0, stream>>>(fm, P);
    wt_transform<<<9216, 256, 0, stream>>>(conv_w, Wt);
    head_wt<<<128, 256, 0, stream>>>(cls_w, reg_w, cls_b, reg_b, W2, b2);
    conv_gemm8<<<dim3(119, 2), 512, 0, stream>>>(P, Wt, conv_b, F);
    head_decode<<<476, 256, 0, stream>>>(F, W2, b2, img, out);
}

// Round 8
// 199.318 us; speedup vs baseline: 1.2845x; 1.0098x over previous
//
#include <hip/hip_runtime.h>

// ---------------- types / helpers ----------------
typedef __attribute__((ext_vector_type(8))) __bf16 bf16x8;
typedef __attribute__((ext_vector_type(4))) float  f32x4;

#define GPTR(p)   (__attribute__((address_space(1))) void*)(p)
#define LDSPTR(p) (__attribute__((address_space(3))) void*)(p)
#define MFMA16 __builtin_amdgcn_mfma_f32_16x16x32_bf16
#define SB() __builtin_amdgcn_sched_barrier(0)
// phase boundary: pin schedule, raw barrier (no drain), pin again
#define PHB() do { SB(); __builtin_amdgcn_s_barrier(); SB(); } while (0)

__device__ __forceinline__ unsigned short f2bf(float f) {
    union { float f; unsigned u; } v; v.f = f;
    unsigned r = v.u + 0x7FFF + ((v.u >> 16) & 1);   // RNE
    return (unsigned short)(r >> 16);
}

// Problem constants
#define MTOT   30400
#define MPAD   30464
#define KTOT   4608
#define NT     72          // K tiles of 64

// ---------------- 1) NCHW f32 -> padded NHWC bf16 ----------------
__global__ __launch_bounds__(256) void pad_transpose(
    const float* __restrict__ in, unsigned short* __restrict__ P)
{
    __shared__ float t[32][33];
    const int tx = threadIdx.x;          // 32
    const int ty = threadIdx.y;          // 8
    const int tix = blockIdx.x % 3;      // x tile
    const int cix = blockIdx.x / 3;      // c tile
    const int y = blockIdx.y;
    const int b = blockIdx.z;
    const int x0 = tix * 32, c0 = cix * 32;

    const int x = x0 + tx;
    if (x < 76) {
#pragma unroll
        for (int i = 0; i < 4; ++i) {
            int c = c0 + ty + i * 8;
            t[ty + i * 8][tx] = in[((b * 512 + c) * 50 + y) * 76 + x];
        }
    }
    __syncthreads();
#pragma unroll
    for (int i = 0; i < 4; ++i) {
        int xr = ty + i * 8;
        int xw = x0 + xr;
        if (xw < 76) {
            P[((b * 52 + y + 1) * 78 + (xw + 1)) * 512 + c0 + tx] = f2bf(t[tx][xr]);
        }
    }
}

// ---------------- 1b) zero only the pad borders of P ----------------
__global__ __launch_bounds__(256) void border_zero(unsigned short* __restrict__ P)
{
    int i = blockIdx.x * 256 + threadIdx.x;      // < 8*256*64 = 131072
    int b   = i >> 14;
    int rem = i & 16383;
    int seg = rem >> 6;                          // 0..255
    int c8  = (rem & 63) << 3;                   // channel base (8 bf16 per float4)
    int y, x;
    if (seg < 78)       { y = 0;  x = seg; }
    else if (seg < 156) { y = 51; x = seg - 78; }
    else if (seg < 206) { y = seg - 155; x = 0; }    // y=1..50
    else                { y = seg - 205; x = 77; }   // y=1..50
    *(float4*)(P + ((b * 52 + y) * 78 + x) * 512 + c8) = make_float4(0.f, 0.f, 0.f, 0.f);
}

// ---------------- 2) conv_w (O,C,3,3) f32 -> Wt[o][kk*512+c] bf16 (B^T layout) ----------------
__global__ __launch_bounds__(256) void wt_transform(
    const float* __restrict__ cw, unsigned short* __restrict__ Wt)
{
    int i = blockIdx.x * 256 + threadIdx.x;       // < 512*4608
    int o = i / KTOT;
    int r = i - o * KTOT;
    int kk = r >> 9;          // 0..8  (ky*3+kx)
    int c  = r & 511;
    Wt[i] = f2bf(cw[(o * 512 + c) * 9 + kk]);
}

// ---------------- 3) head weights -> W2[64][512] bf16 ----------------
__global__ __launch_bounds__(256) void head_wt(
    const float* __restrict__ cls_w, const float* __restrict__ reg_w,
    const float* __restrict__ cls_b, const float* __restrict__ reg_b,
    unsigned short* __restrict__ W2, float* __restrict__ b2)
{
    int i = blockIdx.x * 256 + threadIdx.x;       // < 64*512
    int n = i >> 9, k = i & 511;
    float v = 0.f;
    if (n < 18) v = cls_w[n * 512 + k];
    else if (n < 54) v = reg_w[(n - 18) * 512 + k];
    W2[i] = f2bf(v);
    if (i < 64) {
        float bv = 0.f;
        if (i < 18) bv = cls_b[i];
        else if (i < 54) bv = reg_b[i - 18];
        b2[i] = bv;
    }
}

// ---------------- 4) conv implicit GEMM, 256x256 balanced 8-phase ----------------
// BM=BN=256, BK=64, 8 waves (2M x 4N). LDS 128KB: buf d at d*65536; A at +0,
// B at +32768 (2 halves x 16KB each). st_16x32 XOR swizzle via pre-swizzled
// global source (rule #21). Reads balanced 8/4/8/4: b0 of tile gt+1 is
// early-read at P4(gt) from the NEXT buffer after its vmcnt publication.
// Stage discipline: every LDS overwrite >=1 full barrier after that region's
// last ds_read.  Stages: P1: A(gt+1)h1->next; P3: B(gt+2)h0->cur;
// P4: B(gt+2)h1 + A(gt+2)h0 -> cur.
// FIFO ledger (loads; each st call = 2): entering gt: [B+1h0,B+1h1,A+1h0]=6.
//   P1:+A+1h1=8 | P3:+B+2h0=10, vmcnt(6) retires B(gt+1)=4 -> 6
//   P4: early-read b0(gt+1); +B+2h1,+A+2h0=10, vmcnt(6) retires A(gt+1) -> 6.
//   Tail gt=70: P3 vmcnt(4), P4 vmcnt(0); gt=71: no stages/waits; exit at 0.
// NOTE: macro body uses `gt` (NOT `g`) — TILE_BODY(g,...) with an inner
// `const int g = (G)` self-initializes (rounds 5/6 bug).
__global__ __launch_bounds__(512, 2) void conv_gemm8(
    const unsigned short* __restrict__ P,    // padded NHWC bf16
    const unsigned short* __restrict__ Wt,   // [512][4608] bf16
    const float* __restrict__ bias,
    unsigned short* __restrict__ F)          // [MPAD][512] bf16
{
    __shared__ __attribute__((aligned(1024))) unsigned char lds[131072];

    const int tid = threadIdx.x;
    const int l   = tid & 63;
    const int w   = tid >> 6;          // wave 0..7
    const int wr  = w >> 2;            // M group 0..1 (owns 128 rows = one A half)
    const int nc  = w & 3;             // N group 0..3 (owns 64 cols)
    const int hB  = nc >> 1;           // which B half this wave reads
    const int rB  = (nc & 1) * 4;      // subtile-R base within the B half

    // bijective XCD-chunked block swizzle (nwg=238=8*29+6, m204 formula)
    const int orig = blockIdx.y * 119 + blockIdx.x;
    const int xcd = orig & 7, seq = orig >> 3;
    const int wg  = (xcd < 6 ? xcd * 30 : 180 + (xcd - 6) * 29) + seq;
    const int m0  = (wg % 119) * 256;
    const int n0  = (wg / 119) * 256;

    // swizzled read lane offset within a 1024B subtile
    const int loff = (l & 15) * 64 + (((l >> 4) * 16) ^ ((l & 8) ? 32 : 0));
    // swizzled stage source k-element offset (inverse of read swizzle)
    const int kelS = ((l & 3) * 8) ^ ((l & 32) ? 16 : 0);

    // Per-thread global base offsets for staging (half h, load j).
    int cbA[2][2], nbB[2][2];
#pragma unroll
    for (int h = 0; h < 2; ++h)
#pragma unroll
        for (int j = 0; j < 2; ++j) {
            const int s    = j * 8 + w;                          // subtile 0..15
            const int rowt = h * 128 + (s >> 1) * 16 + (l >> 2); // row in 256-tile
            int m = m0 + rowt; if (m >= MTOT) m = 0;             // clamp (stores guarded)
            int b = m / 3800; int r = m - b * 3800;
            int y = r / 76;   int x = r - y * 76;
            cbA[h][j] = ((b * 52 + y + 1) * 78 + (x + 1)) * 512 + (s & 1) * 32 + kelS;
            nbB[h][j] = (n0 + rowt) * KTOT + (s & 1) * 32 + kelS;
        }

    auto stA = [&](int t, int h, unsigned char* abase) {
        const int kk  = t >> 3;
        const int tap = ((kk / 3 - 1) * 78 + (kk % 3 - 1)) * 512 + (t & 7) * 64;
#pragma unroll
        for (int j = 0; j < 2; ++j)
            __builtin_amdgcn_global_load_lds(GPTR(P + cbA[h][j] + tap),
                LDSPTR(abase + h * 16384 + j * 8192 + w * 1024), 16, 0, 0);
    };
    auto stB = [&](int t, int h, unsigned char* bbase) {
#pragma unroll
        for (int j = 0; j < 2; ++j)
            __builtin_amdgcn_global_load_lds(GPTR(Wt + nbB[h][j] + t * 64),
                LDSPTR(bbase + h * 16384 + j * 8192 + w * 1024), 16, 0, 0);
    };

    f32x4 acc[8][4];
#pragma unroll
    for (int i = 0; i < 8; ++i)
#pragma unroll
        for (int j = 0; j < 4; ++j) acc[i][j] = (f32x4){0.f, 0.f, 0.f, 0.f};

#define RD(basep, subR, ks) (*(const bf16x8*)((basep) + (((subR) * 2 + (ks)) * 1024) + loff))

    bf16x8 b0x[2][2], b0y[2][2];   // alternating b0cur/b0nxt register sets

    // ---- prologue: tile0 (B0h0,B0h1,A0h0,A0h1) + B1h0,B1h1,A1h0; retire tile0 ----
    {
        unsigned char* A0b = lds;
        unsigned char* B0b = lds + 32768;
        unsigned char* A1b = lds + 65536;
        unsigned char* B1b = lds + 65536 + 32768;
        stB(0, 0, B0b); stB(0, 1, B0b); stA(0, 0, A0b); stA(0, 1, A0b);
        stB(1, 0, B1b); stB(1, 1, B1b); stA(1, 0, A1b);
        SB();
        asm volatile("s_waitcnt vmcnt(6)" ::: "memory");   // tile 0 (oldest 8) landed
        __builtin_amdgcn_s_barrier();
        SB();
#pragma unroll
        for (int ni = 0; ni < 2; ++ni)
#pragma unroll
            for (int ks = 0; ks < 2; ++ks)
                b0x[ni][ks] = RD(B0b + hB * 16384, rB + ni, ks);
    }

#define TILE_BODY(G, B0C, B0N)                                                  \
    {                                                                           \
        const int gt = (G);                                                     \
        unsigned char* Ac = lds + (gt & 1) * 65536;                             \
        unsigned char* Bc = Ac + 32768;                                         \
        unsigned char* An = lds + ((gt & 1) ^ 1) * 65536;                       \
        unsigned char* Bn = An + 32768;                                         \
        unsigned char* Ah = Ac + wr * 16384;                                    \
        unsigned char* Bh = Bc + hB * 16384;                                    \
        unsigned char* BhN = Bn + hB * 16384;                                   \
        bf16x8 a[4][2], bb1[2][2];                                              \
        /* ---- P1: read a0 (8); stage A(gt+1)h1->next; MFMA Q1 = a0 x b0cur */ \
        _Pragma("unroll")                                                       \
        for (int f = 0; f < 4; ++f)                                             \
            _Pragma("unroll")                                                   \
            for (int ks = 0; ks < 2; ++ks) a[f][ks] = RD(Ah, f, ks);            \
        if (gt + 1 < NT) stA(gt + 1, 1, An);                                    \
        PHB();                                                                  \
        __builtin_amdgcn_s_setprio(1);                                          \
        _Pragma("unroll")                                                       \
        for (int f = 0; f < 4; ++f)                                             \
            _Pragma("unroll")                                                   \
            for (int ni = 0; ni < 2; ++ni)                                      \
                _Pragma("unroll")                                               \
                for (int ks = 0; ks < 2; ++ks)                                  \
                    acc[f][ni] = MFMA16(a[f][ks], B0C[ni][ks], acc[f][ni], 0, 0, 0); \
        __builtin_amdgcn_s_setprio(0);                                          \
        PHB();                                                                  \
        /* ---- P2: read bb1 (4); NO stage; MFMA Q2 = a0 x bb1 */               \
        _Pragma("unroll")                                                       \
        for (int ni = 0; ni < 2; ++ni)                                          \
            _Pragma("unroll")                                                   \
            for (int ks = 0; ks < 2; ++ks) bb1[ni][ks] = RD(Bh, rB + 2 + ni, ks); \
        PHB();                                                                  \
        __builtin_amdgcn_s_setprio(1);                                          \
        _Pragma("unroll")                                                       \
        for (int f = 0; f < 4; ++f)                                             \
            _Pragma("unroll")                                                   \
            for (int ni = 0; ni < 2; ++ni)                                      \
                _Pragma("unroll")                                               \
                for (int ks = 0; ks < 2; ++ks)                                  \
                    acc[f][2 + ni] = MFMA16(a[f][ks], bb1[ni][ks], acc[f][2 + ni], 0, 0, 0); \
        __builtin_amdgcn_s_setprio(0);                                          \
        PHB();                                                                  \
        /* ---- P3: read a1 (8); stage B(gt+2)h0->cur (half0's bb1 readers      \
                done at P2, barrier since; b0cur readers done P4(gt-1));        \
                MFMA Q3 = a1 x bb1; end: vmcnt publishes B(gt+1) */             \
        _Pragma("unroll")                                                       \
        for (int f = 0; f < 4; ++f)                                             \
            _Pragma("unroll")                                                   \
            for (int ks = 0; ks < 2; ++ks) a[f][ks] = RD(Ah, 4 + f, ks);        \
        if (gt + 2 < NT) stB(gt + 2, 0, Bc);                                    \
        PHB();                                                                  \
        __builtin_amdgcn_s_setprio(1);                                          \
        _Pragma("unroll")                                                       \
        for (int f = 0; f < 4; ++f)                                             \
            _Pragma("unroll")                                                   \
            for (int ni = 0; ni < 2; ++ni)                                      \
                _Pragma("unroll")                                               \
                for (int ks = 0; ks < 2; ++ks)                                  \
                    acc[4 + f][2 + ni] = MFMA16(a[f][ks], bb1[ni][ks], acc[4 + f][2 + ni], 0, 0, 0); \
        __builtin_amdgcn_s_setprio(0);                                          \
        SB();                                                                   \
        if (gt + 2 < NT)      asm volatile("s_waitcnt vmcnt(6)" ::: "memory");  \
        else if (gt + 1 < NT) asm volatile("s_waitcnt vmcnt(4)" ::: "memory");  \
        __builtin_amdgcn_s_barrier();                                           \
        SB();                                                                   \
        /* ---- P4: early-read b0(gt+1) (4, NEXT buf, just published);          \
                stage B(gt+2)h1 + A(gt+2)h0 -> cur (last reads P2/P3,           \
                barrier since); MFMA Q4 = a1 x b0cur; end: publish A(gt+1) */   \
        if (gt + 1 < NT) {                                                      \
            _Pragma("unroll")                                                   \
            for (int ni = 0; ni < 2; ++ni)                                      \
                _Pragma("unroll")                                               \
                for (int ks = 0; ks < 2; ++ks)                                  \
                    B0N[ni][ks] = RD(BhN, rB + ni, ks);                         \
        }                                                                       \
        if (gt + 2 < NT) { stB(gt + 2, 1, Bc); stA(gt + 2, 0, Ac); }            \
        PHB();                                                                  \
        __builtin_amdgcn_s_setprio(1);                                          \
        _Pragma("unroll")                                                       \
        for (int f = 0; f < 4; ++f)                                             \
            _Pragma("unroll")                                                   \
            for (int ni = 0; ni < 2; ++ni)                                      \
                _Pragma("unroll")                                               \
                for (int ks = 0; ks < 2; ++ks)                                  \
                    acc[4 + f][ni] = MFMA16(a[f][ks], B0C[ni][ks], acc[4 + f][ni], 0, 0, 0); \
        __builtin_amdgcn_s_setprio(0);                                          \
        SB();                                                                   \
        if (gt + 2 < NT)      asm volatile("s_waitcnt vmcnt(6)" ::: "memory");  \
        else if (gt + 1 < NT) asm volatile("s_waitcnt vmcnt(0)" ::: "memory");  \
        __builtin_amdgcn_s_barrier();                                           \
        SB();                                                                   \
    }

    for (int g = 0; g < NT; g += 2) {
        TILE_BODY(g,     b0x, b0y)
        TILE_BODY(g + 1, b0y, b0x)
    }
#undef TILE_BODY
#undef RD

    // ---- epilogue: bias + relu + bf16 store ----
#pragma unroll
    for (int ni = 0; ni < 4; ++ni) {
        const int col = n0 + nc * 64 + ni * 16 + (l & 15);
        const float bcol = bias[col];
#pragma unroll
        for (int mi = 0; mi < 8; ++mi) {
#pragma unroll
            for (int jj = 0; jj < 4; ++jj) {
                const int row = m0 + wr * 128 + mi * 16 + (l >> 4) * 4 + jj;
                if (row < MTOT)
                    F[row * 512 + col] = f2bf(fmaxf(acc[mi][ni][jj] + bcol, 0.f));
            }
        }
    }
}

// ---------------- 5) head GEMM (N=54 in 64) + anchor decode ----------------
__global__ __launch_bounds__(256) void head_decode(
    const unsigned short* __restrict__ F,
    const unsigned short* __restrict__ W2,
    const float* __restrict__ b2,
    const int* __restrict__ img,
    float* __restrict__ out)
{
    __shared__ float S[64][56];
    const int tid  = threadIdx.x;
    const int lane = tid & 63;
    const int wv   = tid >> 6;
    const int mblk = blockIdx.x * 64;
    const int arow = mblk + wv * 16 + (lane & 15);   // < MPAD

    f32x4 acc[4];
#pragma unroll
    for (int ni = 0; ni < 4; ++ni) acc[ni] = (f32x4){0.f, 0.f, 0.f, 0.f};

#pragma unroll 4
    for (int ks = 0; ks < 16; ++ks) {
        const int kloc = ks * 32 + (lane >> 4) * 8;
        bf16x8 a = *(const bf16x8*)(F + arow * 512 + kloc);
#pragma unroll
        for (int ni = 0; ni < 4; ++ni) {
            bf16x8 b = *(const bf16x8*)(W2 + (ni * 16 + (lane & 15)) * 512 + kloc);
            acc[ni] = MFMA16(a, b, acc[ni], 0, 0, 0);
        }
    }

#pragma unroll
    for (int ni = 0; ni < 4; ++ni) {
        int col = ni * 16 + (lane & 15);
        if (col < 54) {
            float bb = b2[col];
#pragma unroll
            for (int j = 0; j < 4; ++j)
                S[wv * 16 + (lane >> 4) * 4 + j][col] = acc[ni][j] + bb;
        }
    }
    __syncthreads();

    for (int it = tid; it < 576; it += 256) {
        int rowl = it / 9;
        int a    = it - rowl * 9;
        int m = mblk + rowl;
        if (m >= MTOT) continue;
        int b   = m / 3800;
        int rem = m - b * 3800;
        int y = rem / 76;
        int x = rem - y * 76;

        int ri = a / 3, si = a - ri * 3;
        float sqr = (ri == 0) ? 0.70710678118654752f : ((ri == 1) ? 1.f : 1.41421356237309515f);
        float scale = (float)(128 << si);
        float wa = scale / sqr;
        float ha = scale * sqr;
        float ax = (float)x * 16.f + 8.f;
        float ay = (float)y * 16.f + 8.f;

        float r0 = S[rowl][18 + a * 4 + 0];
        float r1 = S[rowl][18 + a * 4 + 1];
        float r2 = S[rowl][18 + a * 4 + 2];
        float r3 = S[rowl][18 + a * 4 + 3];

        float px = ax + r0 * wa;
        float py = ay + r1 * ha;
        float pw = wa * expf(r2);
        float ph = ha * expf(r3);

        float x1 = px - 0.5f * pw, y1 = py - 0.5f * ph;
        float x2 = x1 + pw,        y2 = y1 + ph;
        float imx = (float)img[2 * b], imy = (float)img[2 * b + 1];
        x1 = fminf(fmaxf(x1, 0.f), imx); x2 = fminf(fmaxf(x2, 0.f), imx);
        y1 = fminf(fmaxf(y1, 0.f), imy); y2 = fminf(fmaxf(y2, 0.f), imy);
        float ww = x2 - x1, hh = y2 - y1;
        float cx = x1 + 0.5f * ww, cy = y1 + 0.5f * hh;

        int pidx = b * 34200 + rem * 9 + a;
        ((float4*)out)[pidx] = make_float4(cx, cy, ww, hh);
        float* oc = out + 1094400 + pidx * 2;
        oc[0] = S[rowl][a * 2 + 0];
        oc[1] = S[rowl][a * 2 + 1];
    }
}

// ---------------- launcher ----------------
extern "C" void kernel_launch(void* const* d_in, const int* in_sizes, int n_in,
                              void* d_out, int out_size, void* d_ws, size_t ws_size,
                              hipStream_t stream) {
    const float* fm     = (const float*)d_in[0];
    const float* conv_w = (const float*)d_in[1];
    const float* conv_b = (const float*)d_in[2];
    const float* cls_w  = (const float*)d_in[3];
    const float* cls_b  = (const float*)d_in[4];
    const float* reg_w  = (const float*)d_in[5];
    const float* reg_b  = (const float*)d_in[6];
    const int*   img    = (const int*)d_in[7];
    float* out = (float*)d_out;

    char* ws = (char*)d_ws;
    unsigned short* P  = (unsigned short*)(ws);
    unsigned short* Wt = (unsigned short*)(ws + 33226752);
    unsigned short* F  = (unsigned short*)(ws + 37945344);
    unsigned short* W2 = (unsigned short*)(ws + 69140480);
    float*          b2 = (float*)(ws + 69206016);

    // zero F tail rows (read by head_decode, never written)
    hipMemsetAsync((char*)F + (size_t)MTOT * 512 * 2, 0, (size_t)(MPAD - MTOT) * 512 * 2, stream);

    border_zero<<<512, 256, 0, stream>>>(P);
    pad_transpose<<<dim3(48, 50, 8), dim3(32, 8, 1), 0, stream>>>(fm, P);
    wt_transform<<<9216, 256, 0, stream>>>(conv_w, Wt);
    head_wt<<<128, 256, 0, stream>>>(cls_w, reg_w, cls_b, reg_b, W2, b2);
    conv_gemm8<<<dim3(119, 2), 512, 0, stream>>>(P, Wt, conv_b, F);
    head_decode<<<476, 256, 0, stream>>>(F, W2, b2, img, out);
}